// Round 4
// baseline (341.280 us; speedup 1.0000x reference)
//
#include <hip/hip_runtime.h>
#include <cstdint>
#include <cmath>

#define Q_ 300
#define C_ 80
#define QC (Q_ * C_)
#define K_ 300
#define HM 160
#define WM 160
#define NBUCK 8192
#define CAND 2048
#define TOPK_THREADS 512

typedef float f32x4_t __attribute__((ext_vector_type(4)));

// -------- Kernel 1: per-batch top-K over sigmoid(logits) --------
__global__ __launch_bounds__(TOPK_THREADS) void topk_kernel(
    const float* __restrict__ logits,   // [B,Q,C]
    const float* __restrict__ boxes_in, // [B,Q,4] cxcywh
    float* __restrict__ out,            // labels[B,K] | boxes[B,K,4] | scores[B,K]
    int* __restrict__ meta,             // [B*K,5] : q, x1,y1,x2,y2
    int B, int S)
{
    int b = blockIdx.x;
    int tid = threadIdx.x;
    __shared__ unsigned int hist[NBUCK];
    __shared__ unsigned int csum[TOPK_THREADS];
    __shared__ unsigned long long cand[CAND];
    __shared__ unsigned int candCount;
    __shared__ int bstar;

    for (int i = tid; i < NBUCK; i += TOPK_THREADS) hist[i] = 0u;
    if (tid == 0) { candCount = 0u; bstar = 0; }
    __syncthreads();

    const float* lg = logits + (size_t)b * QC;

    // histogram over top 13 bits of score bit pattern (monotone for positive floats)
    for (int i = tid; i < QC; i += TOPK_THREADS) {
        float x = lg[i];
        float s = 1.0f / (1.0f + expf(-x));
        unsigned int bits = __float_as_uint(s);
        atomicAdd(&hist[bits >> 19], 1u);
    }
    __syncthreads();

    // per-thread chunk of 16 buckets -> chunk sum
    unsigned int chunkSum = 0u;
    int base = tid * (NBUCK / TOPK_THREADS);
#pragma unroll
    for (int j = 0; j < NBUCK / TOPK_THREADS; ++j) chunkSum += hist[base + j];
    csum[tid] = chunkSum;
    __syncthreads();

    // suffix-inclusive scan: csum[t] = sum_{t'>=t}
    for (int off = 1; off < TOPK_THREADS; off <<= 1) {
        unsigned int v = (tid + off < TOPK_THREADS) ? csum[tid + off] : 0u;
        __syncthreads();
        csum[tid] += v;
        __syncthreads();
    }

    // locate threshold bucket: cumAbove < K <= cumAbove + count
    unsigned int run = (tid < TOPK_THREADS - 1) ? csum[tid + 1] : 0u;
    for (int j = NBUCK / TOPK_THREADS - 1; j >= 0; --j) {
        unsigned int c = hist[base + j];
        if (run < (unsigned)K_ && run + c >= (unsigned)K_) bstar = base + j;  // unique writer
        run += c;
    }
    __syncthreads();
    int bs = bstar;

    // gather candidates; key = score_bits<<32 | (UINT_MAX - idx)
    for (int i = tid; i < QC; i += TOPK_THREADS) {
        float x = lg[i];
        float s = 1.0f / (1.0f + expf(-x));
        unsigned int bits = __float_as_uint(s);
        if ((int)(bits >> 19) >= bs) {
            unsigned int pos = atomicAdd(&candCount, 1u);
            if (pos < CAND)
                cand[pos] = ((unsigned long long)bits << 32)
                          | (unsigned long long)(0xFFFFFFFFu - (unsigned int)i);
        }
    }
    __syncthreads();
    unsigned int n = candCount; if (n > CAND) n = CAND;

    // adaptive sort size (smallest pow2 >= max(n, 512))
    unsigned int size = 512u;
    while (size < n) size <<= 1;
    for (unsigned int i = tid + n; i < size; i += TOPK_THREADS) cand[i] = 0ull;
    __syncthreads();

    // bitonic sort, descending
    for (unsigned int kk = 2; kk <= size; kk <<= 1) {
        for (unsigned int j = kk >> 1; j > 0; j >>= 1) {
            for (unsigned int i = tid; i < size; i += TOPK_THREADS) {
                unsigned int ixj = i ^ j;
                if (ixj > i) {
                    unsigned long long a = cand[i], c = cand[ixj];
                    bool up = ((i & kk) == 0u);
                    bool sw = up ? (a < c) : (a > c);
                    if (sw) { cand[i] = c; cand[ixj] = a; }
                }
            }
            __syncthreads();
        }
    }

    // emit
    float Sf = (float)S;
    float* out_labels = out;
    float* out_boxes  = out + (size_t)B * K_;
    float* out_scores = out + (size_t)B * K_ * 5;
    if (tid < K_) {
        unsigned long long key = cand[tid];
        unsigned int bits = (unsigned int)(key >> 32);
        unsigned int idx  = 0xFFFFFFFFu - (unsigned int)(key & 0xFFFFFFFFull);
        int label = (int)(idx % C_);
        int q     = (int)(idx / C_);
        const float* bx = boxes_in + ((size_t)b * Q_ + q) * 4;
        float cx = bx[0], cy = bx[1], bw = bx[2], bh = bx[3];
        float x1 = (cx - bw * 0.5f) * Sf;
        float y1 = (cy - bh * 0.5f) * Sf;
        float x2 = (cx + bw * 0.5f) * Sf;
        float y2 = (cy + bh * 0.5f) * Sf;
        int o = b * K_ + tid;
        out_labels[o] = (float)label;
        out_scores[o] = __uint_as_float(bits);
        out_boxes[(size_t)o * 4 + 0] = x1;
        out_boxes[(size_t)o * 4 + 1] = y1;
        out_boxes[(size_t)o * 4 + 2] = x2;
        out_boxes[(size_t)o * 4 + 3] = y2;
        int xi1 = min(max((int)truncf(x1), 0), S);
        int yi1 = min(max((int)truncf(y1), 0), S);
        int xi2 = min(max((int)truncf(x2), 0), S);
        int yi2 = min(max((int)truncf(y2), 0), S);
        meta[(size_t)o * 5 + 0] = q;
        meta[(size_t)o * 5 + 1] = xi1;
        meta[(size_t)o * 5 + 2] = yi1;
        meta[(size_t)o * 5 + 3] = xi2;
        meta[(size_t)o * 5 + 4] = yi2;
    }
}

// -------- Kernel 2 (S=512): 4x4-px units, 3x3 source window, zero fast paths --------
__global__ __launch_bounds__(256) void mask_kernel_512(
    const float* __restrict__ masks,  // [B,Q,HM,WM]
    const int* __restrict__ meta,     // [B*K,5]
    float* __restrict__ out_masks)    // [B*K,512,512]
{
    constexpr int S = 512;
    constexpr float ISC = 0.3125f;  // HM/S exact
    int bk = blockIdx.x;
    int yt = blockIdx.y;
    int b = bk / K_;
    const int* m = meta + (size_t)bk * 5;
    int q  = m[0];
    int x1 = m[1], y1 = m[2], x2 = m[3], y2 = m[4];
    const float* src = masks + ((size_t)b * Q_ + q) * (HM * WM);
    float* dst = out_masks + (size_t)bk * S * S;
    int yb0 = yt << 5;  // 32 rows per block

    bool nzY = (y1 < yb0 + 32) && (y2 > yb0) && (y1 < y2);
    bool nzX = (x1 < x2) && (x1 < S) && (x2 > 0);
    if (!(nzY && nzX)) {
        // whole tile outside crop: pure zero fill at stream rate
        f32x4_t z = (f32x4_t)(0.0f);
        f32x4_t* base = reinterpret_cast<f32x4_t*>(dst + (size_t)yb0 * S);
        for (int t = threadIdx.x; t < 32 * 128; t += 256)
            __builtin_nontemporal_store(z, base + t);
        return;
    }

    // 8 row-units x 128 col-units; lanes map to consecutive col-units -> coalesced stores
    for (int u = threadIdx.x; u < 1024; u += 256) {
        int g  = u & 127;
        int ru = u >> 7;
        int y0 = yb0 + (ru << 2);
        int x0 = g << 2;

        bool anyRow = (y1 < y0 + 4) && (y2 > y0);
        bool anyCol = (x0 < x2) && (x0 + 4 > x1);

        if (anyRow && anyCol) {
            // ---- x window: 3 source cols shared by 4 px ----
            float ib = (x0 + 0.5f) * ISC - 0.5f;
            int fb = (int)floorf(ib);
            int j0 = max(fb, 0);
            int j1 = min(fb + 1, WM - 1);
            int j2 = min(fb + 2, WM - 1);
            // ---- y window: 3 source rows shared by 4 rows ----
            float iy0f = (y0 + 0.5f) * ISC - 0.5f;
            int f0 = (int)floorf(iy0f);
            int r0i = max(f0, 0);
            int r1i = min(f0 + 1, HM - 1);
            int r2i = min(f0 + 2, HM - 1);

            const float* p0 = src + (size_t)r0i * WM;
            const float* p1 = src + (size_t)r1i * WM;
            const float* p2 = src + (size_t)r2i * WM;
            float A00 = p0[j0], A01 = p0[j1], A02 = p0[j2];
            float A10 = p1[j0], A11 = p1[j1], A12 = p1[j2];
            float A20 = p2[j0], A21 = p2[j1], A22 = p2[j2];

            // horizontal interp for the 3 source rows (per-px weights shared vertically)
            float hv0[4], hv1[4], hv2[4];
            bool colIn[4];
#pragma unroll
            for (int c = 0; c < 4; ++c) {
                int x = x0 + c;
                float ix  = (x + 0.5f) * ISC - 0.5f;
                float fxf = floorf(ix);
                float fx  = ix - fxf;
                int o = (int)fxf - fb;  // 0 or 1
                float wx0 = 1.0f - fx, wx1 = fx;
                float a0 = o ? A01 : A00, b0v = o ? A02 : A01;
                float a1 = o ? A11 : A10, b1v = o ? A12 : A11;
                float a2 = o ? A21 : A20, b2v = o ? A22 : A21;
                hv0[c] = wx0 * a0 + wx1 * b0v;
                hv1[c] = wx0 * a1 + wx1 * b1v;
                hv2[c] = wx0 * a2 + wx1 * b2v;
                colIn[c] = (x >= x1) && (x < x2);
            }

#pragma unroll
            for (int rr = 0; rr < 4; ++rr) {
                int y = y0 + rr;
                f32x4_t r4 = (f32x4_t)(0.0f);
                if (y >= y1 && y < y2) {
                    float iy  = (y + 0.5f) * ISC - 0.5f;
                    float fyf = floorf(iy);
                    float fy  = iy - fyf;
                    int oy = (int)fyf - f0;  // 0 or 1
                    float wy0 = 1.0f - fy, wy1 = fy;
#pragma unroll
                    for (int c = 0; c < 4; ++c) {
                        float ha = oy ? hv1[c] : hv0[c];
                        float hb = oy ? hv2[c] : hv1[c];
                        float val = wy0 * ha + wy1 * hb;
                        r4[c] = (colIn[c] && val > 0.0f) ? 1.0f : 0.0f;
                    }
                }
                __builtin_nontemporal_store(
                    r4, reinterpret_cast<f32x4_t*>(dst + (size_t)y * S + x0));
            }
        } else {
            f32x4_t z = (f32x4_t)(0.0f);
#pragma unroll
            for (int rr = 0; rr < 4; ++rr)
                __builtin_nontemporal_store(
                    z, reinterpret_cast<f32x4_t*>(dst + (size_t)(y0 + rr) * S + x0));
        }
    }
}

// -------- Generic fallback (round-1 validated path) --------
__global__ __launch_bounds__(256) void mask_kernel_generic(
    const float* __restrict__ masks,
    const int* __restrict__ meta,
    float* __restrict__ out_masks,
    int S, int rowsPerTile)
{
    int bk = blockIdx.x;
    int ytile = blockIdx.y;
    int b = bk / K_;
    const int* m = meta + (size_t)bk * 5;
    int q  = m[0];
    int x1 = m[1], y1 = m[2], x2 = m[3], y2 = m[4];
    const float* src = masks + ((size_t)b * Q_ + q) * (HM * WM);
    float* dst = out_masks + (size_t)bk * S * S;
    float inv_scale = (float)((double)HM / (double)S);

    int qx = S >> 2;
    int total = rowsPerTile * qx;
    for (int t = threadIdx.x; t < total; t += 256) {
        int ry = t / qx;
        int xq = t - ry * qx;
        int y  = ytile * rowsPerTile + ry;
        int x0 = xq << 2;
        float4 r = make_float4(0.0f, 0.0f, 0.0f, 0.0f);
        if (y >= y1 && y < y2) {
            float iy  = (y + 0.5f) * inv_scale - 0.5f;
            float fyf = floorf(iy);
            int   y0i = (int)fyf;
            float fy  = iy - fyf;
            int ya = max(y0i, 0);
            int yb = min(y0i + 1, HM - 1);
            const float* r0 = src + (size_t)ya * WM;
            const float* r1 = src + (size_t)yb * WM;
            float wy0 = 1.0f - fy, wy1 = fy;
            float v[4];
#pragma unroll
            for (int c = 0; c < 4; ++c) {
                int x = x0 + c;
                float vv = 0.0f;
                if (x >= x1 && x < x2) {
                    float ix  = (x + 0.5f) * inv_scale - 0.5f;
                    float fxf = floorf(ix);
                    int   x0i = (int)fxf;
                    float fx  = ix - fxf;
                    int xa = max(x0i, 0);
                    int xb = min(x0i + 1, WM - 1);
                    float wx0 = 1.0f - fx, wx1 = fx;
                    float top = wx0 * r0[xa] + wx1 * r0[xb];
                    float bot = wx0 * r1[xa] + wx1 * r1[xb];
                    float val = wy0 * top + wy1 * bot;
                    vv = (val > 0.0f) ? 1.0f : 0.0f;
                }
                v[c] = vv;
            }
            r = make_float4(v[0], v[1], v[2], v[3]);
        }
        *reinterpret_cast<float4*>(dst + (size_t)y * S + x0) = r;
    }
}

extern "C" void kernel_launch(void* const* d_in, const int* in_sizes, int n_in,
                              void* d_out, int out_size, void* d_ws, size_t ws_size,
                              hipStream_t stream) {
    const float* pred_logits = (const float*)d_in[0];
    const float* pred_boxes  = (const float*)d_in[1];
    const float* pred_masks  = (const float*)d_in[2];

    int B = in_sizes[0] / QC;
    long long mask_elems = (long long)out_size - (long long)B * K_ * 6;
    int S = (int)llroundf(sqrtf((float)(mask_elems / ((long long)B * K_))));
    if (S <= 0) S = 512;

    float* out = (float*)d_out;
    int* meta = (int*)d_ws;

    topk_kernel<<<dim3(B), dim3(TOPK_THREADS), 0, stream>>>(
        pred_logits, pred_boxes, out, meta, B, S);

    float* out_masks = out + (size_t)B * K_ * 6;
    if (S == 512) {
        mask_kernel_512<<<dim3(B * K_, 16), dim3(256), 0, stream>>>(
            pred_masks, meta, out_masks);
    } else {
        int rowsPerTile = 32;
        int ntile = (S + rowsPerTile - 1) / rowsPerTile;
        mask_kernel_generic<<<dim3(B * K_, ntile), dim3(256), 0, stream>>>(
            pred_masks, meta, out_masks, S, rowsPerTile);
    }
}

// Round 5
// 307.840 us; speedup vs baseline: 1.1086x; 1.1086x over previous
//
#include <hip/hip_runtime.h>
#include <cstdint>
#include <cmath>

#define Q_ 300
#define C_ 80
#define QC (Q_ * C_)
#define K_ 300
#define HM 160
#define WM 160
#define NBUCK 8192
#define CAND 2048
#define TOPK_THREADS 512

typedef float f32x4_t __attribute__((ext_vector_type(4)));

// -------- Kernel 1: per-batch top-K over sigmoid(logits) --------
__global__ __launch_bounds__(TOPK_THREADS) void topk_kernel(
    const float* __restrict__ logits,   // [B,Q,C]
    const float* __restrict__ boxes_in, // [B,Q,4] cxcywh
    float* __restrict__ out,            // labels[B,K] | boxes[B,K,4] | scores[B,K]
    int* __restrict__ meta,             // [B*K,5] : q, x1,y1,x2,y2
    int B, int S)
{
    int b = blockIdx.x;
    int tid = threadIdx.x;
    __shared__ unsigned int hist[NBUCK];
    __shared__ unsigned int csum[TOPK_THREADS];
    __shared__ unsigned long long cand[CAND];
    __shared__ unsigned int candCount;
    __shared__ int bstar;

    for (int i = tid; i < NBUCK; i += TOPK_THREADS) hist[i] = 0u;
    if (tid == 0) { candCount = 0u; bstar = 0; }
    __syncthreads();

    const float* lg = logits + (size_t)b * QC;

    // histogram over top 13 bits of score bit pattern (monotone for positive floats)
    for (int i = tid; i < QC; i += TOPK_THREADS) {
        float x = lg[i];
        float s = 1.0f / (1.0f + expf(-x));
        unsigned int bits = __float_as_uint(s);
        atomicAdd(&hist[bits >> 19], 1u);
    }
    __syncthreads();

    // per-thread chunk of 16 buckets -> chunk sum
    unsigned int chunkSum = 0u;
    int base = tid * (NBUCK / TOPK_THREADS);
#pragma unroll
    for (int j = 0; j < NBUCK / TOPK_THREADS; ++j) chunkSum += hist[base + j];
    csum[tid] = chunkSum;
    __syncthreads();

    // suffix-inclusive scan: csum[t] = sum_{t'>=t}
    for (int off = 1; off < TOPK_THREADS; off <<= 1) {
        unsigned int v = (tid + off < TOPK_THREADS) ? csum[tid + off] : 0u;
        __syncthreads();
        csum[tid] += v;
        __syncthreads();
    }

    // locate threshold bucket: cumAbove < K <= cumAbove + count
    unsigned int run = (tid < TOPK_THREADS - 1) ? csum[tid + 1] : 0u;
    for (int j = NBUCK / TOPK_THREADS - 1; j >= 0; --j) {
        unsigned int c = hist[base + j];
        if (run < (unsigned)K_ && run + c >= (unsigned)K_) bstar = base + j;  // unique writer
        run += c;
    }
    __syncthreads();
    int bs = bstar;

    // gather candidates; key = score_bits<<32 | (UINT_MAX - idx)
    for (int i = tid; i < QC; i += TOPK_THREADS) {
        float x = lg[i];
        float s = 1.0f / (1.0f + expf(-x));
        unsigned int bits = __float_as_uint(s);
        if ((int)(bits >> 19) >= bs) {
            unsigned int pos = atomicAdd(&candCount, 1u);
            if (pos < CAND)
                cand[pos] = ((unsigned long long)bits << 32)
                          | (unsigned long long)(0xFFFFFFFFu - (unsigned int)i);
        }
    }
    __syncthreads();
    unsigned int n = candCount; if (n > CAND) n = CAND;

    // adaptive sort size (smallest pow2 >= max(n, 512))
    unsigned int size = 512u;
    while (size < n) size <<= 1;
    for (unsigned int i = tid + n; i < size; i += TOPK_THREADS) cand[i] = 0ull;
    __syncthreads();

    // bitonic sort, descending
    for (unsigned int kk = 2; kk <= size; kk <<= 1) {
        for (unsigned int j = kk >> 1; j > 0; j >>= 1) {
            for (unsigned int i = tid; i < size; i += TOPK_THREADS) {
                unsigned int ixj = i ^ j;
                if (ixj > i) {
                    unsigned long long a = cand[i], c = cand[ixj];
                    bool up = ((i & kk) == 0u);
                    bool sw = up ? (a < c) : (a > c);
                    if (sw) { cand[i] = c; cand[ixj] = a; }
                }
            }
            __syncthreads();
        }
    }

    // emit
    float Sf = (float)S;
    float* out_labels = out;
    float* out_boxes  = out + (size_t)B * K_;
    float* out_scores = out + (size_t)B * K_ * 5;
    if (tid < K_) {
        unsigned long long key = cand[tid];
        unsigned int bits = (unsigned int)(key >> 32);
        unsigned int idx  = 0xFFFFFFFFu - (unsigned int)(key & 0xFFFFFFFFull);
        int label = (int)(idx % C_);
        int q     = (int)(idx / C_);
        const float* bx = boxes_in + ((size_t)b * Q_ + q) * 4;
        float cx = bx[0], cy = bx[1], bw = bx[2], bh = bx[3];
        float x1 = (cx - bw * 0.5f) * Sf;
        float y1 = (cy - bh * 0.5f) * Sf;
        float x2 = (cx + bw * 0.5f) * Sf;
        float y2 = (cy + bh * 0.5f) * Sf;
        int o = b * K_ + tid;
        out_labels[o] = (float)label;
        out_scores[o] = __uint_as_float(bits);
        out_boxes[(size_t)o * 4 + 0] = x1;
        out_boxes[(size_t)o * 4 + 1] = y1;
        out_boxes[(size_t)o * 4 + 2] = x2;
        out_boxes[(size_t)o * 4 + 3] = y2;
        int xi1 = min(max((int)truncf(x1), 0), S);
        int yi1 = min(max((int)truncf(y1), 0), S);
        int xi2 = min(max((int)truncf(x2), 0), S);
        int yi2 = min(max((int)truncf(y2), 0), S);
        meta[(size_t)o * 5 + 0] = q;
        meta[(size_t)o * 5 + 1] = xi1;
        meta[(size_t)o * 5 + 2] = yi1;
        meta[(size_t)o * 5 + 3] = xi2;
        meta[(size_t)o * 5 + 4] = yi2;
    }
}

// -------- Kernel 2 (S=512): round-3 loop + block/chunk zero fast paths --------
__global__ __launch_bounds__(256) void mask_kernel_512(
    const float* __restrict__ masks,  // [B,Q,HM,WM]
    const int* __restrict__ meta,     // [B*K,5]
    float* __restrict__ out_masks)    // [B*K,512,512]
{
    constexpr int S = 512;
    constexpr float ISC = 0.3125f;  // HM/S exact
    int bk = blockIdx.x;
    int yt = blockIdx.y;
    int b = bk / K_;
    const int* m = meta + (size_t)bk * 5;
    int q  = m[0];
    int x1 = m[1], y1 = m[2], x2 = m[3], y2 = m[4];
    const float* src = masks + ((size_t)b * Q_ + q) * (HM * WM);
    float* dst = out_masks + (size_t)bk * S * S;
    int yb0 = yt << 5;  // 32 rows per block

    // Block-level fast path: whole 32-row stripe is zero
    bool stripeLive = (y1 < yb0 + 32) && (y2 > yb0) && (y1 < y2) &&
                      (x1 < x2) && (x1 < S) && (x2 > 0);
    if (!stripeLive) {
        f32x4_t z = (f32x4_t)(0.0f);
        f32x4_t* base = reinterpret_cast<f32x4_t*>(dst + (size_t)yb0 * S);
        for (int t = threadIdx.x; t < 32 * 128; t += 256)
            __builtin_nontemporal_store(z, base + t);
        return;
    }

    // 32 rows x 128 float4-chunks; wave-uniform row test, per-lane x-window test
    for (int t = threadIdx.x; t < 32 * 128; t += 256) {
        int ry = t >> 7;
        int xq = t & 127;
        int y  = yb0 + ry;
        int x0 = xq << 2;
        f32x4_t r = (f32x4_t)(0.0f);
        if (y >= y1 && y < y2 && x0 + 4 > x1 && x0 < x2) {
            float iy  = (y + 0.5f) * ISC - 0.5f;
            float fyf = floorf(iy);
            int   y0i = (int)fyf;
            float fy  = iy - fyf;
            int ya = max(y0i, 0);
            int yb = min(y0i + 1, HM - 1);
            const float* r0 = src + (size_t)ya * WM;
            const float* r1 = src + (size_t)yb * WM;
            float wy0 = 1.0f - fy, wy1 = fy;

            // 3-wide input window shared by the 4 pixels
            float ib  = (x0 + 0.5f) * ISC - 0.5f;
            int   fb  = (int)floorf(ib);
            int i0 = max(fb, 0);
            int i1 = min(fb + 1, WM - 1);
            int i2 = min(fb + 2, WM - 1);
            float a0 = r0[i0], a1 = r0[i1], a2 = r0[i2];
            float b0 = r1[i0], b1 = r1[i1], b2 = r1[i2];

            float v[4];
#pragma unroll
            for (int c = 0; c < 4; ++c) {
                int x = x0 + c;
                float vv = 0.0f;
                if (x >= x1 && x < x2) {
                    float ix  = (x + 0.5f) * ISC - 0.5f;
                    float fxf = floorf(ix);
                    int   x0i = (int)fxf;
                    float fx  = ix - fxf;
                    int o = x0i - fb;           // 0 or 1
                    float va = o ? a1 : a0;
                    float vb = o ? a2 : a1;
                    float wa = o ? b1 : b0;
                    float wb = o ? b2 : b1;
                    float wx0 = 1.0f - fx, wx1 = fx;
                    float top = wx0 * va + wx1 * vb;
                    float bot = wx0 * wa + wx1 * wb;
                    float val = wy0 * top + wy1 * bot;
                    vv = (val > 0.0f) ? 1.0f : 0.0f;
                }
                v[c] = vv;
            }
            r = (f32x4_t){v[0], v[1], v[2], v[3]};
        }
        __builtin_nontemporal_store(r, reinterpret_cast<f32x4_t*>(dst + (size_t)y * S + x0));
    }
}

// -------- Generic fallback (round-1 validated path) --------
__global__ __launch_bounds__(256) void mask_kernel_generic(
    const float* __restrict__ masks,
    const int* __restrict__ meta,
    float* __restrict__ out_masks,
    int S, int rowsPerTile)
{
    int bk = blockIdx.x;
    int ytile = blockIdx.y;
    int b = bk / K_;
    const int* m = meta + (size_t)bk * 5;
    int q  = m[0];
    int x1 = m[1], y1 = m[2], x2 = m[3], y2 = m[4];
    const float* src = masks + ((size_t)b * Q_ + q) * (HM * WM);
    float* dst = out_masks + (size_t)bk * S * S;
    float inv_scale = (float)((double)HM / (double)S);

    int qx = S >> 2;
    int total = rowsPerTile * qx;
    for (int t = threadIdx.x; t < total; t += 256) {
        int ry = t / qx;
        int xq = t - ry * qx;
        int y  = ytile * rowsPerTile + ry;
        int x0 = xq << 2;
        float4 r = make_float4(0.0f, 0.0f, 0.0f, 0.0f);
        if (y >= y1 && y < y2) {
            float iy  = (y + 0.5f) * inv_scale - 0.5f;
            float fyf = floorf(iy);
            int   y0i = (int)fyf;
            float fy  = iy - fyf;
            int ya = max(y0i, 0);
            int yb = min(y0i + 1, HM - 1);
            const float* r0 = src + (size_t)ya * WM;
            const float* r1 = src + (size_t)yb * WM;
            float wy0 = 1.0f - fy, wy1 = fy;
            float v[4];
#pragma unroll
            for (int c = 0; c < 4; ++c) {
                int x = x0 + c;
                float vv = 0.0f;
                if (x >= x1 && x < x2) {
                    float ix  = (x + 0.5f) * inv_scale - 0.5f;
                    float fxf = floorf(ix);
                    int   x0i = (int)fxf;
                    float fx  = ix - fxf;
                    int xa = max(x0i, 0);
                    int xb = min(x0i + 1, WM - 1);
                    float wx0 = 1.0f - fx, wx1 = fx;
                    float top = wx0 * r0[xa] + wx1 * r0[xb];
                    float bot = wx0 * r1[xa] + wx1 * r1[xb];
                    float val = wy0 * top + wy1 * bot;
                    vv = (val > 0.0f) ? 1.0f : 0.0f;
                }
                v[c] = vv;
            }
            r = make_float4(v[0], v[1], v[2], v[3]);
        }
        *reinterpret_cast<float4*>(dst + (size_t)y * S + x0) = r;
    }
}

extern "C" void kernel_launch(void* const* d_in, const int* in_sizes, int n_in,
                              void* d_out, int out_size, void* d_ws, size_t ws_size,
                              hipStream_t stream) {
    const float* pred_logits = (const float*)d_in[0];
    const float* pred_boxes  = (const float*)d_in[1];
    const float* pred_masks  = (const float*)d_in[2];

    int B = in_sizes[0] / QC;
    long long mask_elems = (long long)out_size - (long long)B * K_ * 6;
    int S = (int)llroundf(sqrtf((float)(mask_elems / ((long long)B * K_))));
    if (S <= 0) S = 512;

    float* out = (float*)d_out;
    int* meta = (int*)d_ws;

    topk_kernel<<<dim3(B), dim3(TOPK_THREADS), 0, stream>>>(
        pred_logits, pred_boxes, out, meta, B, S);

    float* out_masks = out + (size_t)B * K_ * 6;
    if (S == 512) {
        mask_kernel_512<<<dim3(B * K_, 16), dim3(256), 0, stream>>>(
            pred_masks, meta, out_masks);
    } else {
        int rowsPerTile = 32;
        int ntile = (S + rowsPerTile - 1) / rowsPerTile;
        mask_kernel_generic<<<dim3(B * K_, ntile), dim3(256), 0, stream>>>(
            pred_masks, meta, out_masks, S, rowsPerTile);
    }
}